// Round 8
// baseline (429.257 us; speedup 1.0000x reference)
//
#include <hip/hip_runtime.h>
#include <hip/hip_bf16.h>
#include <cfloat>
#include <stdint.h>

#define EPS 1e-5f
constexpr int Dd = 512, Tt = 1024, Kk = 8192;
constexpr int Nq = 16 * 1024;
constexpr float TAU = 1.5f;   // ~7 sigma of 1-product bf16 error + key quant

typedef __bf16 bf16x8 __attribute__((ext_vector_type(8)));
typedef float  f32x4  __attribute__((ext_vector_type(4)));
typedef unsigned long long u64;

union Pack8 { __bf16 h[8]; int4 v; };

__device__ __forceinline__ void gld16(const void* g, void* l) {
    __builtin_amdgcn_global_load_lds(
        (const __attribute__((address_space(1))) uint32_t*)g,
        (__attribute__((address_space(3))) uint32_t*)l, 16, 0, 0);
}

// ---- monotone fp32 -> u32 key helpers --------------------------------------
__device__ __forceinline__ unsigned monokey(float s) {
    unsigned b = __float_as_uint(s);
    return b ^ ((unsigned)((int)b >> 31) | 0x80000000u);
}
__device__ __forceinline__ float unmono(unsigned u) {
    u = (u & 0x80000000u) ? (u ^ 0x80000000u) : ~u;
    return __uint_as_float(u);
}

// ---- sorted-pair / sorted-quad merges --------------------------------------
__device__ __forceinline__ void merge2u(unsigned& a1, unsigned& a2, unsigned b1, unsigned b2) {
    unsigned c1 = min(a1, b1);
    unsigned c2 = min(max(a1, b1), min(a2, b2));
    a1 = c1; a2 = c2;
}
__device__ __forceinline__ u64 umin64(u64 a, u64 b) { return a < b ? a : b; }
__device__ __forceinline__ u64 umax64(u64 a, u64 b) { return a > b ? a : b; }
__device__ __forceinline__ void merge4q(u64& a1, u64& a2, u64& a3, u64& a4,
                                        u64 b1, u64 b2, u64 b3, u64 b4) {
    u64 c1 = umin64(a1, b1);
    u64 c2 = umin64(umin64(a2, b2), umax64(a1, b1));
    u64 c3 = umin64(umin64(a3, b3), umin64(umax64(a2, b1), umax64(a1, b2)));
    u64 c4 = umin64(umin64(a4, b4), umin64(umax64(a3, b1), umax64(a1, b3)));
    c4 = umin64(c4, umax64(a2, b2));
    a1 = c1; a2 = c2; a3 = c3; a4 = c4;
}
__device__ __forceinline__ u64 shflx64(u64 v, int m) {
    int lo = __shfl_xor((int)(unsigned)v, m, 64);
    int hi = __shfl_xor((int)(v >> 32), m, 64);
    return ((u64)(unsigned)hi << 32) | (unsigned)lo;
}

// ---------------- P0: fused prep — x transpose/convert + emb build ----------
__global__ __launch_bounds__(256) void prep_kernel(const float* __restrict__ x,
                                                   const float* __restrict__ es,
                                                   const float* __restrict__ usage,
                                                   ushort* __restrict__ Xh,
                                                   float* __restrict__ Xf,
                                                   ushort* __restrict__ Eh,
                                                   float* __restrict__ embf,
                                                   double* __restrict__ e2d,
                                                   float* __restrict__ e2f,
                                                   int* __restrict__ cnt) {
    __shared__ float Ls[64][68];
    const int tid = threadIdx.x;
    if (blockIdx.x < 2048) {
        // ---- split_x part: x (B,D,T) -> Xh bf16 + Xf fp32, both (B*T, D) ---
        const int bid = blockIdx.x;
        if (bid == 0 && tid < 2) cnt[tid] = 0;
        const int b  = bid >> 7;
        const int d0 = ((bid >> 4) & 7) * 64;
        const int t0 = (bid & 15) * 64;
        const float* xb = x + ((size_t)b * Dd + d0) * Tt + t0;
#pragma unroll
        for (int it = 0; it < 4; ++it) {
            int s = it * 256 + tid;
            int d = s >> 4, c = (s & 15) * 4;
            float4 g = *(const float4*)(xb + (size_t)d * Tt + c);
            *(float4*)&Ls[d][c] = g;
        }
        __syncthreads();
        const int t = tid >> 2;
        const int dseg = (tid & 3) * 16;
        Pack8 ph[2];
        float vf[16];
#pragma unroll
        for (int dd = 0; dd < 16; ++dd) {
            float v = Ls[dseg + dd][t];
            vf[dd] = v;
            ph[dd >> 3].h[dd & 7] = (__bf16)v;
        }
        size_t base = ((size_t)(b * Tt + t0 + t)) * Dd + d0 + dseg;
        *(int4*)(Xh + base)     = ph[0].v;
        *(int4*)(Xh + base + 8) = ph[1].v;
#pragma unroll
        for (int g = 0; g < 4; ++g)
            *(float4*)(Xf + base + g * 4) = make_float4(vf[g*4], vf[g*4+1], vf[g*4+2], vf[g*4+3]);
    } else {
        // ---- split_e part: emb=es/clip(u) -> Eh bf16 + embf fp32 + e2 ------
        const int wave = tid >> 6, lane = tid & 63;
        const int k = (blockIdx.x - 2048) * 4 + wave;
        const float uc = fmaxf(usage[k], EPS);
        const float* row = es + (size_t)k * Dd;
        const int d = lane * 8;
        float4 a = *(const float4*)(row + d);
        float4 c = *(const float4*)(row + d + 4);
        float ef[8] = {a.x/uc, a.y/uc, a.z/uc, a.w/uc, c.x/uc, c.y/uc, c.z/uc, c.w/uc};
        Pack8 ph;
        double e2 = 0.0;
#pragma unroll
        for (int j = 0; j < 8; ++j) {
            ph.h[j] = (__bf16)ef[j];
            e2 = fma((double)ef[j], (double)ef[j], e2);
        }
        size_t base = (size_t)k * Dd + d;
        *(int4*)(Eh + base) = ph.v;
        *(float4*)(embf + base)     = make_float4(ef[0], ef[1], ef[2], ef[3]);
        *(float4*)(embf + base + 4) = make_float4(ef[4], ef[5], ef[6], ef[7]);
#pragma unroll
        for (int off = 32; off >= 1; off >>= 1) e2 += __shfl_down(e2, off, 64);
        if (lane == 0) { e2d[k] = e2; e2f[k] = (float)e2; }
    }
}

// ---------------- main GEMM: 128x128, 1-product bf16, top-2 epilogue --------
// Block swizzle: 8mb x 8nb supertiles, nb-outer; lid&7 spreads nb across XCDs.
__global__ __launch_bounds__(256) void gemm_kernel(const ushort* __restrict__ Xh,
                                                   const ushort* __restrict__ Eh,
                                                   const float* __restrict__ e2f,
                                                   uint2* __restrict__ colres) {
    __shared__ ushort Ahs[128 * 32], Bhs[128 * 32];
    __shared__ unsigned trip[2][128][2];

    const int tid = threadIdx.x;
    const int g = blockIdx.x;
    const int lid = g & 63;
    const int snb = lid & 7, smb = lid >> 3;       // XCD = blockIdx % 8 = snb
    const int super = g >> 6;                      // 128 supertiles, nb-outer
    const int sup_mb = super & 15, sup_nb = super >> 4;
    const int mb = sup_mb * 8 + smb;               // 0..127
    const int nb = sup_nb * 8 + snb;               // 0..63
    const int m0 = mb * 128, n0 = nb * 128;
    const int wave = tid >> 6, lane = tid & 63;
    const int mw = (wave >> 1) * 64, nw = (wave & 1) * 64;
    const int fm = lane & 15, fq = lane >> 4;
    const int cphys = (fq ^ ((fm >> 1) & 3)) * 8;  // read-side XOR swizzle

    f32x4 acc[4][4] = {};

    for (int d0 = 0; d0 < Dd; d0 += 32) {
#pragma unroll
        for (int j = 0; j < 2; ++j) {
            int s = j * 256 + tid;
            int r = s >> 2;
            int c = ((s & 3) ^ ((s >> 3) & 3)) * 8;  // store-side swizzle
            size_t ga = (size_t)(m0 + r) * Dd + d0 + c;
            size_t gb = (size_t)(n0 + r) * Dd + d0 + c;
            gld16(Xh + ga, (char*)Ahs + s * 16);
            gld16(Eh + gb, (char*)Bhs + s * 16);
        }
        __syncthreads();
        bf16x8 ah[4], bh[4];
#pragma unroll
        for (int i = 0; i < 4; ++i) {
            int ra = (mw + i * 16 + fm) * 32 + cphys;
            int rb = (nw + i * 16 + fm) * 32 + cphys;
            ah[i] = *(const bf16x8*)&Ahs[ra];
            bh[i] = *(const bf16x8*)&Bhs[rb];
        }
#pragma unroll
        for (int i = 0; i < 4; ++i)
#pragma unroll
            for (int j = 0; j < 4; ++j)
                acc[i][j] = __builtin_amdgcn_mfma_f32_16x16x32_bf16(ah[i], bh[j], acc[i][j], 0, 0, 0);
        __syncthreads();
    }

    float e2r[4];
#pragma unroll
    for (int j = 0; j < 4; ++j) e2r[j] = e2f[n0 + nw + j * 16 + fm];

    // top-2 per (row, 128-col block); u32 keys, low 7 bits = col-in-block
#pragma unroll
    for (int i = 0; i < 4; ++i)
#pragma unroll
        for (int r = 0; r < 4; ++r) {
            unsigned k[4];
#pragma unroll
            for (int j = 0; j < 4; ++j) {
                float s = fmaf(-2.0f, acc[i][j][r], e2r[j]);
                k[j] = (monokey(s) & 0xFFFFFF80u) | (unsigned)(nw + j * 16 + fm);
            }
            unsigned lo01 = min(k[0], k[1]), hi01 = max(k[0], k[1]);
            unsigned lo23 = min(k[2], k[3]), hi23 = max(k[2], k[3]);
            unsigned a1 = min(lo01, lo23);
            unsigned a2 = min(max(lo01, lo23), min(hi01, hi23));
#pragma unroll
            for (int st = 1; st < 16; st <<= 1) {
                unsigned b1 = __shfl_xor(a1, st, 64);
                unsigned b2 = __shfl_xor(a2, st, 64);
                merge2u(a1, a2, b1, b2);
            }
            if (fm == 0) {
                int rl = mw + i * 16 + fq * 4 + r;
                trip[wave & 1][rl][0] = a1;
                trip[wave & 1][rl][1] = a2;
            }
        }
    __syncthreads();
    if (tid < 128) {
        unsigned a1 = trip[0][tid][0], a2 = trip[0][tid][1];
        merge2u(a1, a2, trip[1][tid][0], trip[1][tid][1]);
        colres[(size_t)(m0 + tid) * 64 + nb] = make_uint2(a1, a2);
    }
}

// ------- merge: global top-4 + collision ballot; inline fp64 cand rescore ---
__global__ __launch_bounds__(256) void merge_kernel(const uint2* __restrict__ colres,
                                                    const float* __restrict__ Xf,
                                                    const float* __restrict__ embf,
                                                    const double* __restrict__ e2d,
                                                    float* __restrict__ out,
                                                    int* __restrict__ cnt,
                                                    int* __restrict__ queueF,
                                                    int* __restrict__ fmark) {
    const int wave = threadIdx.x >> 6, lane = threadIdx.x & 63;
    const int row = blockIdx.x * 4 + wave;
    uint2 q = colres[(size_t)row * 64 + lane];
    const unsigned nb128 = (unsigned)(lane * 128);
    u64 a1 = ((u64)(q.x & 0xFFFFFF80u) << 32) | (nb128 + (q.x & 127u));
    u64 a2 = ((u64)(q.y & 0xFFFFFF80u) << 32) | (nb128 + (q.y & 127u));
    u64 a3 = ~0ull, a4 = ~0ull;
#pragma unroll
    for (int st = 1; st < 64; st <<= 1)
        merge4q(a1, a2, a3, a4, shflx64(a1, st), shflx64(a2, st), shflx64(a3, st), shflx64(a4, st));
    // all lanes now hold the identical global top-4
    float v1 = unmono((unsigned)(a1 >> 32));
    float v2 = unmono((unsigned)(a2 >> 32));
    float v4 = unmono((unsigned)(a4 >> 32));
    u64 coll = __ballot(unmono(q.y) < v1 + TAU);   // block has 2+ near-min entries
    const int i1 = (int)(unsigned)a1;
    const bool fscanT = (coll != 0ull) || (v4 - v1 < TAU);
    const bool candT = !fscanT && (v2 - v1 < TAU);
    if (lane == 0) {
        out[row] = (float)i1;
        int fmv = 0;
        if (fscanT) { int p = atomicAdd(&cnt[1], 1); queueF[p] = row; fmv = p + 1; }
        fmark[row] = fmv;
    }
    if (candT) {
        // winner provably in {i1..i4}: exact fp64 rescore inline (whole wave)
        int ci[4] = {i1, (int)(unsigned)a2, (int)(unsigned)a3, (int)(unsigned)a4};
        const float* xr = Xf + (size_t)row * Dd + lane * 8;
        float4 xv0 = *(const float4*)xr;
        float4 xv1 = *(const float4*)(xr + 4);
        double s[4] = {0.0, 0.0, 0.0, 0.0};
#pragma unroll
        for (int c = 0; c < 4; ++c) {
            const float* er = embf + (size_t)ci[c] * Dd + lane * 8;
            float4 ea = *(const float4*)er;
            float4 eb = *(const float4*)(er + 4);
            double t = 0.0;
            t = fma((double)xv0.x, (double)ea.x, t);
            t = fma((double)xv0.y, (double)ea.y, t);
            t = fma((double)xv0.z, (double)ea.z, t);
            t = fma((double)xv0.w, (double)ea.w, t);
            t = fma((double)xv1.x, (double)eb.x, t);
            t = fma((double)xv1.y, (double)eb.y, t);
            t = fma((double)xv1.z, (double)eb.z, t);
            t = fma((double)xv1.w, (double)eb.w, t);
            s[c] = t;
        }
#pragma unroll
        for (int off = 32; off >= 1; off >>= 1) {
#pragma unroll
            for (int c = 0; c < 4; ++c) s[c] += __shfl_down(s[c], off, 64);
        }
        if (lane == 0) {
            double bv = DBL_MAX; int bi = 0x7fffffff;
#pragma unroll
            for (int c = 0; c < 4; ++c) {
                double dv = fma(-2.0, s[c], e2d[ci[c]]);
                if (dv < bv || (dv == bv && ci[c] < bi)) { bv = dv; bi = ci[c]; }
            }
            out[row] = (float)bi;
        }
    }
}

// ---------------- rare full exact scan: 16 chunks x 512 clusters per query --
__global__ __launch_bounds__(256) void fscan_kernel(const float* __restrict__ Xf,
                                                    const float* __restrict__ embf,
                                                    const double* __restrict__ e2d,
                                                    const int* __restrict__ cnt,
                                                    const int* __restrict__ queueF,
                                                    double* __restrict__ fbv,
                                                    int* __restrict__ fbi) {
    __shared__ float xs[512];
    __shared__ double sv[256];
    __shared__ int si[256];
    const int tid = threadIdx.x;
    const int ntask = cnt[1] * 16;
    for (int task = blockIdx.x; task < ntask; task += gridDim.x) {
        int qi = task >> 4, ch = task & 15;
        int row = queueF[qi];
        __syncthreads();
        for (int d = tid; d < Dd; d += 256)
            xs[d] = Xf[(size_t)row * Dd + d];
        __syncthreads();
        double bv = DBL_MAX; int bi = 0x7fffffff;
#pragma unroll
        for (int c = 0; c < 2; ++c) {
            int k = ch * 512 + c * 256 + tid;
            const float* er = embf + (size_t)k * Dd;
            double a0 = 0, a1 = 0, a2 = 0, a3 = 0;
            for (int d = 0; d < Dd; d += 4) {
                float4 e = *(const float4*)(er + d);
                float4 xv = *(const float4*)&xs[d];
                a0 = fma((double)e.x, (double)xv.x, a0);
                a1 = fma((double)e.y, (double)xv.y, a1);
                a2 = fma((double)e.z, (double)xv.z, a2);
                a3 = fma((double)e.w, (double)xv.w, a3);
            }
            double s = fma(-2.0, (a0 + a1) + (a2 + a3), e2d[k]);
            if (s < bv || (s == bv && k < bi)) { bv = s; bi = k; }
        }
        sv[tid] = bv; si[tid] = bi;
        __syncthreads();
        for (int off = 128; off > 0; off >>= 1) {
            if (tid < off) {
                if (sv[tid + off] < sv[tid] ||
                    (sv[tid + off] == sv[tid] && si[tid + off] < si[tid])) {
                    sv[tid] = sv[tid + off]; si[tid] = si[tid + off];
                }
            }
            __syncthreads();
        }
        if (tid == 0) { fbv[task] = sv[0]; fbi[task] = si[0]; }
    }
}

// ------- gather + inline fmerge for flagged rows, coalesced along t ---------
__global__ __launch_bounds__(256) void gather_kernel(const float* __restrict__ embf,
                                                     const int* __restrict__ fmark,
                                                     const double* __restrict__ fbv,
                                                     const int* __restrict__ fbi,
                                                     float* __restrict__ out) {
    __shared__ int cs[64];
    const int tid = threadIdx.x;
    const int m0 = blockIdx.x * 64;
    const int b = m0 >> 10;
    const int t0 = m0 & (Tt - 1);
    if (tid < 64) {
        int row = m0 + tid;
        int fmv = fmark[row];
        int code;
        if (fmv > 0) {                 // finalize fscan result for this row
            int qi = fmv - 1;
            double bv = DBL_MAX; int bi = 0x7fffffff;
            for (int c = 0; c < 16; ++c) {
                double v = fbv[qi * 16 + c]; int i = fbi[qi * 16 + c];
                if (v < bv || (v == bv && i < bi)) { bv = v; bi = i; }
            }
            out[row] = (float)bi;
            code = bi;
        } else {
            code = (int)out[row];
        }
        cs[tid] = code;
    }
    __syncthreads();
    const int tq = tid & 63;
    const int dg = tid >> 6;
    const int c = cs[tq];
    const float* row = embf + (size_t)c * Dd;   // embf == exact fp32 es/clip(u)
    float* ob = out + Nq + (size_t)b * Dd * Tt + t0 + tq;
#pragma unroll 4
    for (int d = dg * 128; d < dg * 128 + 128; ++d)
        ob[(size_t)d * Tt] = row[d];
}

extern "C" void kernel_launch(void* const* d_in, const int* in_sizes, int n_in,
                              void* d_out, int out_size, void* d_ws, size_t ws_size,
                              hipStream_t stream) {
    const float* x     = (const float*)d_in[0];
    const float* es    = (const float*)d_in[1];
    const float* usage = (const float*)d_in[2];
    float* out = (float*)d_out;

    char* w = (char*)d_ws;
    ushort* Xh = (ushort*)w;   w += (size_t)Nq * Dd * 2;      // 16 MB
    ushort* Eh = (ushort*)w;   w += (size_t)Kk * Dd * 2;      //  8 MB
    float*  Xf = (float*)w;    w += (size_t)Nq * Dd * 4;      // 32 MB
    float*  embf = (float*)w;  w += (size_t)Kk * Dd * 4;      // 16 MB
    double* e2d = (double*)w;  w += (size_t)Kk * 8;
    float*  e2f = (float*)w;   w += (size_t)Kk * 4;
    uint2* colres = (uint2*)w; w += (size_t)Nq * 64 * 8;      // 8.4 MB
    int* cnt = (int*)w;        w += 256;
    int* queueF = (int*)w;     w += (size_t)Nq * 4;
    int* fmark = (int*)w;      w += (size_t)Nq * 4;
    // fbv/fbi alias Xh (dead after gemm_kernel; fscan runs strictly later)
    double* fbv = (double*)Xh;                                // worst case 2 MB
    int*    fbi = (int*)((char*)Xh + 4 * 1024 * 1024);        // worst case 1 MB

    prep_kernel<<<4096, 256, 0, stream>>>(x, es, usage, Xh, Xf, Eh, embf, e2d, e2f, cnt);
    gemm_kernel<<<8192, 256, 0, stream>>>(Xh, Eh, e2f, colres);
    merge_kernel<<<Nq / 4, 256, 0, stream>>>(colres, Xf, embf, e2d, out, cnt, queueF, fmark);
    fscan_kernel<<<256, 256, 0, stream>>>(Xf, embf, e2d, cnt, queueF, fbv, fbi);
    gather_kernel<<<Nq / 64, 256, 0, stream>>>(embf, fmark, fbv, fbi, out);
}